// Round 2
// baseline (643.646 us; speedup 1.0000x reference)
//
#include <hip/hip_runtime.h>
#include <cstdint>

#define B_   8
#define K_   512
#define DAPP 768
#define DK   96
#define NT   16          // n-columns per flash block
#define MT   32          // m-rows per inner tile
#define MS   8           // m-split factor (flash-decode style)
#define MCH  (K_ / MS)   // 64 m-rows per block
#define P_F  ((size_t)B_ * K_ * DK)          // 393216 floats per projection
#define SD_OFF (3 * P_F)
#define SD_SZ  ((size_t)B_ * K_ * K_)        // 2097152 floats
#define PART_OFF (SD_OFF + SD_SZ)
#define PART_STRIDE 1568                     // 16*96 acc + 16 m + 16 l

__device__ __forceinline__ float dot4(float4 a, float4 b) {
    return a.x * b.x + a.y * b.y + a.z * b.z + a.w * b.w;
}

// ---------------------------------------------------------------------------
// Kernel 1: projections. w_k is pre-scaled by 1/sqrt(96).
// grid (256,3), block 256.
// ---------------------------------------------------------------------------
__global__ __launch_bounds__(256) void proj_kernel(
    const float* __restrict__ fa,
    const float* __restrict__ WK, const float* __restrict__ WKb,
    const float* __restrict__ WQ, const float* __restrict__ WQb,
    const float* __restrict__ WV, const float* __restrict__ WVb,
    float* __restrict__ ws) {
    const int mat = blockIdx.y;
    const float* W  = (mat == 0) ? WK  : (mat == 1) ? WQ  : WV;
    const float* Wb = (mat == 0) ? WKb : (mat == 1) ? WQb : WVb;
    const float scale = (mat == 0) ? 0.10206207f : 1.0f;   // 1/sqrt(96) folded into w_k
    float* outp = ws + (size_t)mat * P_F;

    const int t  = threadIdx.x;
    const int tr = t >> 4;
    const int tc = t & 15;
    const int row = blockIdx.x * 16 + tr;

    const float4* fa4 = (const float4*)fa + (size_t)row * (DAPP / 4);
    const float4* W4  = (const float4*)W;

    float acc[6] = {0.f, 0.f, 0.f, 0.f, 0.f, 0.f};
    const float4* wrow[6];
#pragma unroll
    for (int j = 0; j < 6; ++j)
        wrow[j] = W4 + (size_t)(tc + 16 * j) * (DAPP / 4);

#pragma unroll 2
    for (int q = 0; q < DAPP / 4; ++q) {
        float4 a = fa4[q];
#pragma unroll
        for (int j = 0; j < 6; ++j)
            acc[j] += dot4(a, wrow[j][q]);
    }
#pragma unroll
    for (int j = 0; j < 6; ++j) {
        int c = tc + 16 * j;
        outp[(size_t)row * DK + c] = (acc[j] + Wb[c]) * scale;
    }
}

// ---------------------------------------------------------------------------
// Kernel 2: sd[b,m,n] = w_k_scaled[b,m] . w_q[b,n]   (8 MB into ws)
// grid B*K (one block per (b,m)), block 256; 8 lanes per n + shfl reduce.
// ---------------------------------------------------------------------------
__global__ __launch_bounds__(256) void sd_kernel(
    const float* __restrict__ wk, const float* __restrict__ wq,
    float* __restrict__ sd) {
    const int bm = blockIdx.x;
    const int b  = bm >> 9;
    const int t = threadIdx.x;
    const int p = t & 7;
    const int nidx = t >> 3;

    const float4* wk4 = (const float4*)wk + (size_t)bm * 24;
    const float4* wq4 = (const float4*)wq;
    float4 kf0 = wk4[p], kf1 = wk4[p + 8], kf2 = wk4[p + 16];
    float* sdr = sd + (size_t)bm * K_;

#pragma unroll 2
    for (int it = 0; it < 16; ++it) {
        const int n = it * 32 + nidx;
        const float4* qr = wq4 + ((size_t)(b * K_ + n)) * 24 + p;
        float s = dot4(qr[0], kf0) + dot4(qr[8], kf1) + dot4(qr[16], kf2);
        s += __shfl_xor(s, 1);
        s += __shfl_xor(s, 2);
        s += __shfl_xor(s, 4);
        if (p == 0) sdr[n] = s;
    }
}

// ---------------------------------------------------------------------------
// Kernel 3: flash over m. One block = (b, 16-col n-tile, 64-row m-chunk).
// grid 2048 = 8b * 8ms * 32nt (nt in low bits -> consecutive blocks stream
// adjacent PE regions), block 256.
// Per 32-row tile: A) gate dot (4-lane frags + 2 shfl) + sd add -> lt[]
//                  B) online softmax update (16-lane groups)
//                  C) PV accumulate from LDS-staged wv tile.
// Writes per-block partials {acc[16][96], m[16], l[16]}.
// ---------------------------------------------------------------------------
__global__ __launch_bounds__(256) void flash_kernel(
    const float* __restrict__ pe,
    const float* __restrict__ WGw, const float* __restrict__ WGb,
    const float* __restrict__ ws_base,
    float* __restrict__ parts) {
    __shared__ float lt[MT][NT + 1];
    __shared__ __align__(16) float wvl[MT][DK];
    __shared__ float s_m[NT], s_l[NT], s_scale[NT];

    const int bid = blockIdx.x;
    const int nt = bid & 31;
    const int ms = (bid >> 5) & 7;
    const int b  = bid >> 8;
    const int n0 = nt * NT;
    const int m0 = ms * MCH;
    const int t = threadIdx.x;

    // phase-A ids: quad lane p, pair -> (nj, mi_h)
    const int p = t & 3;
    const int pairn = (t >> 2) & 15;
    const int pairm = t >> 6;

    // phase-C ids (threads < 192): n-col, octet of 8 d
    const int cn = t / 12;
    const int co = t % 12;

    // wv staging ids: 3 float4 per thread
    int smi[3], sf[3];
#pragma unroll
    for (int r = 0; r < 3; ++r) {
        int idx = t + 256 * r;
        smi[r] = idx / 24;
        sf[r]  = idx % 24;
    }

    const float4* wg4 = (const float4*)WGw;
    float4 gf[6];
#pragma unroll
    for (int j = 0; j < 6; ++j) gf[j] = wg4[p + 4 * j];
    const float gb = WGb[0];

    if (t < NT) { s_m[t] = -1e30f; s_l[t] = 0.f; }

    const float4* pe4 = (const float4*)pe;
    const float*  sd  = ws_base + SD_OFF;
    const float4* wv4 = (const float4*)(ws_base + 2 * P_F);

    float4 accA = {0.f, 0.f, 0.f, 0.f};
    float4 accB = {0.f, 0.f, 0.f, 0.f};

    for (int tile = 0; tile < MCH / MT; ++tile) {
        const int mb = m0 + tile * MT;

        // stage wv tile (32 x 96) into LDS
#pragma unroll
        for (int r = 0; r < 3; ++r)
            ((float4*)wvl)[t + 256 * r] =
                wv4[((size_t)(b * K_ + mb + smi[r])) * 24 + sf[r]];

        // ---- phase A: gate + sd -> lt
#pragma unroll 2
        for (int pass = 0; pass < 8; ++pass) {
            const int mi = pass * 4 + pairm;
            const int m  = mb + mi;
            const float4* pr =
                pe4 + ((size_t)((b * K_ + m) * K_ + n0 + pairn)) * 24 + p;
            float s = dot4(pr[0],  gf[0]) + dot4(pr[4],  gf[1]) +
                      dot4(pr[8],  gf[2]) + dot4(pr[12], gf[3]) +
                      dot4(pr[16], gf[4]) + dot4(pr[20], gf[5]);
            s += __shfl_xor(s, 1);
            s += __shfl_xor(s, 2);
            if (p == 0) {
                float sdv = sd[(size_t)((b * K_ + m) * K_) + n0 + pairn];
                lt[mi][pairn] = __logf(fmaxf(s + gb, 1e-6f)) + sdv;
            }
        }
        __syncthreads();

        // ---- phase B: online softmax update over this tile's 32 rows
        {
            const int n = t >> 4, l = t & 15;
            float v0 = lt[l][n], v1 = lt[l + 16][n];
            float tmax = fmaxf(v0, v1);
            tmax = fmaxf(tmax, __shfl_xor(tmax, 1));
            tmax = fmaxf(tmax, __shfl_xor(tmax, 2));
            tmax = fmaxf(tmax, __shfl_xor(tmax, 4));
            tmax = fmaxf(tmax, __shfl_xor(tmax, 8));
            float mold = s_m[n];
            float mnew = fmaxf(mold, tmax);
            float e0 = __expf(v0 - mnew), e1 = __expf(v1 - mnew);
            float ts = e0 + e1;
            ts += __shfl_xor(ts, 1);
            ts += __shfl_xor(ts, 2);
            ts += __shfl_xor(ts, 4);
            ts += __shfl_xor(ts, 8);
            float sc = __expf(mold - mnew);
            if (l == 0) {
                s_m[n] = mnew;
                s_l[n] = s_l[n] * sc + ts;
                s_scale[n] = sc;
            }
            lt[l][n] = e0;
            lt[l + 16][n] = e1;
        }
        __syncthreads();

        // ---- phase C: rescale + PV accumulate
        if (t < 192) {
            float sc = s_scale[cn];
            accA.x *= sc; accA.y *= sc; accA.z *= sc; accA.w *= sc;
            accB.x *= sc; accB.y *= sc; accB.z *= sc; accB.w *= sc;
#pragma unroll 8
            for (int mi = 0; mi < MT; ++mi) {
                float pv = lt[mi][cn];
                float4 wA = *(const float4*)&wvl[mi][co * 8];
                float4 wB = *(const float4*)&wvl[mi][co * 8 + 4];
                accA.x = fmaf(pv, wA.x, accA.x);
                accA.y = fmaf(pv, wA.y, accA.y);
                accA.z = fmaf(pv, wA.z, accA.z);
                accA.w = fmaf(pv, wA.w, accA.w);
                accB.x = fmaf(pv, wB.x, accB.x);
                accB.y = fmaf(pv, wB.y, accB.y);
                accB.z = fmaf(pv, wB.z, accB.z);
                accB.w = fmaf(pv, wB.w, accB.w);
            }
        }
        __syncthreads();
    }

    // write partials
    float* pp = parts + (size_t)bid * PART_STRIDE;
    if (t < 192) {
        *(float4*)&pp[cn * DK + co * 8]     = accA;
        *(float4*)&pp[cn * DK + co * 8 + 4] = accB;
    }
    if (t >= 192 && t < 192 + NT) {
        int n = t - 192;
        pp[1536 + n] = s_m[n];
        pp[1552 + n] = s_l[n];
    }
}

// ---------------------------------------------------------------------------
// Kernel 4: combine the MS=8 m-split partials. grid B*32, block 192.
// ---------------------------------------------------------------------------
__global__ __launch_bounds__(192) void combine_kernel(
    const float* __restrict__ parts, float* __restrict__ out) {
    const int bid = blockIdx.x;     // b*32 + nt
    const int nt = bid & 31, b = bid >> 5;
    const int t = threadIdx.x;
    const int cn = t / 12, co = t % 12;

    float mv[MS];
    float M = -1e30f;
#pragma unroll
    for (int s = 0; s < MS; ++s) {
        size_t pidx = (size_t)((b * MS + s) * 32 + nt) * PART_STRIDE;
        mv[s] = parts[pidx + 1536 + cn];
        M = fmaxf(M, mv[s]);
    }
    float L = 0.f;
    float4 aA = {0.f, 0.f, 0.f, 0.f};
    float4 aB = {0.f, 0.f, 0.f, 0.f};
#pragma unroll
    for (int s = 0; s < MS; ++s) {
        size_t pidx = (size_t)((b * MS + s) * 32 + nt) * PART_STRIDE;
        float w = __expf(mv[s] - M);
        L += parts[pidx + 1552 + cn] * w;
        float4 xA = *(const float4*)&parts[pidx + cn * DK + co * 8];
        float4 xB = *(const float4*)&parts[pidx + cn * DK + co * 8 + 4];
        aA.x = fmaf(w, xA.x, aA.x); aA.y = fmaf(w, xA.y, aA.y);
        aA.z = fmaf(w, xA.z, aA.z); aA.w = fmaf(w, xA.w, aA.w);
        aB.x = fmaf(w, xB.x, aB.x); aB.y = fmaf(w, xB.y, aB.y);
        aB.z = fmaf(w, xB.z, aB.z); aB.w = fmaf(w, xB.w, aB.w);
    }
    float inv = 1.f / L;
    aA.x *= inv; aA.y *= inv; aA.z *= inv; aA.w *= inv;
    aB.x *= inv; aB.y *= inv; aB.z *= inv; aB.w *= inv;
    float* ob = out + ((size_t)(b * K_) + nt * NT + cn) * DK + co * 8;
    *(float4*)&ob[0] = aA;
    *(float4*)&ob[4] = aB;
}

// ---------------------------------------------------------------------------
extern "C" void kernel_launch(void* const* d_in, const int* in_sizes, int n_in,
                              void* d_out, int out_size, void* d_ws, size_t ws_size,
                              hipStream_t stream) {
    (void)in_sizes; (void)n_in; (void)out_size; (void)ws_size;
    const float* fa  = (const float*)d_in[0];
    const float* pe  = (const float*)d_in[1];
    const float* WGw = (const float*)d_in[2];
    const float* WGb = (const float*)d_in[3];
    const float* WKw = (const float*)d_in[4];
    const float* WKb = (const float*)d_in[5];
    const float* WQw = (const float*)d_in[6];
    const float* WQb = (const float*)d_in[7];
    const float* WVw = (const float*)d_in[8];
    const float* WVb = (const float*)d_in[9];
    float* out = (float*)d_out;
    float* ws  = (float*)d_ws;

    proj_kernel<<<dim3(256, 3), 256, 0, stream>>>(fa, WKw, WKb, WQw, WQb, WVw, WVb, ws);
    sd_kernel<<<B_ * K_, 256, 0, stream>>>(ws, ws + P_F, ws + SD_OFF);
    flash_kernel<<<B_ * MS * 32, 256, 0, stream>>>(pe, WGw, WGb, ws, ws + PART_OFF);
    combine_kernel<<<B_ * 32, 192, 0, stream>>>(ws + PART_OFF, out);
}

// Round 3
// 575.432 us; speedup vs baseline: 1.1185x; 1.1185x over previous
//
#include <hip/hip_runtime.h>
#include <cstdint>

#define B_   8
#define K_   512
#define DAPP 768
#define DK   96
#define DG   96

// ws layout (floats):
//   [0,      P)  : w_k (pre-scaled by 1/sqrt(96))  [B*K][96]
//   [P,     2P)  : w_q   [B*K][96]
//   [2P,    3P)  : w_v   [B*K][96]
//   [3P, 3P+BKK) : logits [B*K][K]   (indexed [b*K+m][n])
#define P_F ((size_t)B_ * K_ * DK)          // 393216 floats
#define LG_OFF (3 * P_F)

typedef float fvec4 __attribute__((ext_vector_type(4)));

__device__ __forceinline__ float dot4(float4 a, float4 b) {
    return a.x * b.x + a.y * b.y + a.z * b.z + a.w * b.w;
}
__device__ __forceinline__ float dot4e(fvec4 a, float4 b) {
    return a.x * b.x + a.y * b.y + a.z * b.z + a.w * b.w;
}

// ---------------------------------------------------------------------------
// Kernel 1: w_k / w_q / w_v projections.  grid (256, 3), block 256.
// w_k pre-scaled by 1/sqrt(96). Each block: 16 rows of f_a; thread (tr,tc) ->
// row tr, cols {tc+16j}. A-loads broadcast across 16 tc lanes; W in L1/L2.
// ---------------------------------------------------------------------------
__global__ __launch_bounds__(256) void proj_kernel(
    const float* __restrict__ fa,
    const float* __restrict__ WK, const float* __restrict__ WKb,
    const float* __restrict__ WQ, const float* __restrict__ WQb,
    const float* __restrict__ WV, const float* __restrict__ WVb,
    float* __restrict__ ws) {
    const int mat = blockIdx.y;
    const float* W  = (mat == 0) ? WK  : (mat == 1) ? WQ  : WV;
    const float* Wb = (mat == 0) ? WKb : (mat == 1) ? WQb : WVb;
    const float scale = (mat == 0) ? 0.10206207f : 1.0f;   // 1/sqrt(96)
    float* outp = ws + (size_t)mat * P_F;

    const int t  = threadIdx.x;
    const int tr = t >> 4;
    const int tc = t & 15;
    const int row = blockIdx.x * 16 + tr;

    const float4* fa4 = (const float4*)fa + (size_t)row * (DAPP / 4);
    const float4* W4  = (const float4*)W;

    float acc[6] = {0.f, 0.f, 0.f, 0.f, 0.f, 0.f};
    const float4* wrow[6];
#pragma unroll
    for (int j = 0; j < 6; ++j)
        wrow[j] = W4 + (size_t)(tc + 16 * j) * (DAPP / 4);

#pragma unroll 2
    for (int q = 0; q < DAPP / 4; ++q) {
        float4 a = fa4[q];
#pragma unroll
        for (int j = 0; j < 6; ++j)
            acc[j] += dot4(a, wrow[j][q]);
    }
#pragma unroll
    for (int j = 0; j < 6; ++j) {
        int c = tc + 16 * j;
        outp[(size_t)row * DK + c] = (acc[j] + Wb[c]) * scale;
    }
}

// ---------------------------------------------------------------------------
// Kernel 2: logits[b,m,n] = log(max(PE[b,m,n,:]·WG + gb, 1e-6))
//                           + w_k_scaled[b,m]·w_q[b,n]
// grid 4096 = B*K (one block per (b,m)), block 256.
// 8 lanes per n; lane p owns f4 fragments {p, p+8, p+16} -> each load instr
// is line-coalesced. PE loads are nontemporal (zero reuse; keep L2 for wq).
// ---------------------------------------------------------------------------
__global__ __launch_bounds__(256) void logits_kernel(
    const float* __restrict__ pe,
    const float* __restrict__ WGw, const float* __restrict__ WGb,
    float* ws) {
    const int bm = blockIdx.x;           // b*K + m
    const int b  = bm >> 9;

    const int t = threadIdx.x;
    const int p = t & 7;                 // 0..7: fragment lane
    const int nidx = t >> 3;             // 0..31: n within tile

    const float4* wk4 = (const float4*)ws + (size_t)bm * 24;
    const float4* wq4 = (const float4*)(ws + P_F);
    const float4* wg4 = (const float4*)WGw;
    const fvec4*  pe4 = (const fvec4*)pe + (size_t)bm * K_ * 24;
    float* lg = ws + LG_OFF + (size_t)bm * K_;

    float4 kf0 = wk4[p], kf1 = wk4[p + 8], kf2 = wk4[p + 16];
    float4 gf0 = wg4[p], gf1 = wg4[p + 8], gf2 = wg4[p + 16];
    const float gb = WGb[0];

    for (int it = 0; it < 16; ++it) {
        const int n = it * 32 + nidx;
        const fvec4* pr = pe4 + (size_t)n * 24 + p;
        fvec4 p0 = __builtin_nontemporal_load(pr);
        fvec4 p1 = __builtin_nontemporal_load(pr + 8);
        fvec4 p2 = __builtin_nontemporal_load(pr + 16);
        float s1 = dot4e(p0, gf0) + dot4e(p1, gf1) + dot4e(p2, gf2);
        const float4* qr = wq4 + ((size_t)(b * K_ + n)) * 24 + p;
        float s2 = dot4(qr[0], kf0) + dot4(qr[8], kf1) + dot4(qr[16], kf2);
        s1 += __shfl_xor(s1, 1); s2 += __shfl_xor(s2, 1);
        s1 += __shfl_xor(s1, 2); s2 += __shfl_xor(s2, 2);
        s1 += __shfl_xor(s1, 4); s2 += __shfl_xor(s2, 4);
        if (p == 0) {
            float gate = fmaxf(s1 + gb, 1e-6f);   // relu + clip combined
            lg[n] = __logf(gate) + s2;            // s2 already scaled via wk
        }
    }
}

// ---------------------------------------------------------------------------
// Kernel 3: softmax over m (per column n) + PV.
// grid B*32 (16-column n-tile per block), block 384.
// LDS tile [512][20] (stride 20 -> 2-way conflicts only, float4-aligned).
// ---------------------------------------------------------------------------
__global__ __launch_bounds__(384) void softmax_pv_kernel(
    const float* __restrict__ ws_c, float* __restrict__ out) {
    __shared__ __align__(16) float sp[512 * 20];
    const int blk = blockIdx.x;
    const int b = blk >> 5;
    const int n0 = (blk & 31) * 16;
    const int t = threadIdx.x;

    const float* logits = ws_c + LG_OFF + (size_t)b * K_ * K_;
    const float4* lg4 = (const float4*)logits;

    // load 512 x 16 logit tile (4 f4 per m-row)
    for (int i = t; i < 2048; i += 384) {
        int mrow = i >> 2, q = i & 3;
        float4 v = lg4[(size_t)mrow * (K_ / 4) + (n0 >> 2) + q];
        *(float4*)&sp[mrow * 20 + q * 4] = v;
    }
    __syncthreads();

    // softmax over m: 16 lanes per column, 16 columns (threads 0..255)
    if (t < 256) {
        const int c = t >> 4, l = t & 15;
        float vals[32];
        float mx = -1e30f;
#pragma unroll
        for (int i = 0; i < 32; ++i) {
            vals[i] = sp[(i * 16 + l) * 20 + c];
            mx = fmaxf(mx, vals[i]);
        }
        mx = fmaxf(mx, __shfl_xor(mx, 8));
        mx = fmaxf(mx, __shfl_xor(mx, 4));
        mx = fmaxf(mx, __shfl_xor(mx, 2));
        mx = fmaxf(mx, __shfl_xor(mx, 1));
        float sum = 0.f;
#pragma unroll
        for (int i = 0; i < 32; ++i) {
            float e = __expf(vals[i] - mx);
            vals[i] = e;
            sum += e;
        }
        sum += __shfl_xor(sum, 8);
        sum += __shfl_xor(sum, 4);
        sum += __shfl_xor(sum, 2);
        sum += __shfl_xor(sum, 1);
        float inv = 1.f / sum;
#pragma unroll
        for (int i = 0; i < 32; ++i)
            sp[(i * 16 + l) * 20 + c] = vals[i] * inv;
    }
    __syncthreads();

    // PV: out[b, n0+g*4+j, d] = sum_m p[m][g*4+j] * wv[b,m,d]
    const int d = t % 96;
    const int g = t / 96;                 // 0..3
    const float* wv = ws_c + 2 * P_F + (size_t)b * K_ * DK;
    float a0 = 0.f, a1 = 0.f, a2 = 0.f, a3 = 0.f;
#pragma unroll 8
    for (int mrow = 0; mrow < 512; ++mrow) {
        float v = wv[(size_t)mrow * DK + d];
        float4 p4 = *(const float4*)&sp[mrow * 20 + g * 4];
        a0 += p4.x * v; a1 += p4.y * v; a2 += p4.z * v; a3 += p4.w * v;
    }
    const int nbase = n0 + g * 4;
    float* ob = out + ((size_t)b * K_ + nbase) * DK + d;
    ob[0]      = a0;
    ob[DK]     = a1;
    ob[2 * DK] = a2;
    ob[3 * DK] = a3;
}

// ---------------------------------------------------------------------------
extern "C" void kernel_launch(void* const* d_in, const int* in_sizes, int n_in,
                              void* d_out, int out_size, void* d_ws, size_t ws_size,
                              hipStream_t stream) {
    (void)in_sizes; (void)n_in; (void)out_size; (void)ws_size;
    const float* fa  = (const float*)d_in[0];
    const float* pe  = (const float*)d_in[1];
    const float* WGw = (const float*)d_in[2];
    const float* WGb = (const float*)d_in[3];
    const float* WKw = (const float*)d_in[4];
    const float* WKb = (const float*)d_in[5];
    const float* WQw = (const float*)d_in[6];
    const float* WQb = (const float*)d_in[7];
    const float* WVw = (const float*)d_in[8];
    const float* WVb = (const float*)d_in[9];
    float* out = (float*)d_out;
    float* ws  = (float*)d_ws;

    proj_kernel<<<dim3(256, 3), 256, 0, stream>>>(fa, WKw, WKb, WQw, WQb, WVw, WVb, ws);
    logits_kernel<<<B_ * K_, 256, 0, stream>>>(pe, WGw, WGb, ws);
    softmax_pv_kernel<<<B_ * 32, 384, 0, stream>>>(ws, out);
}